// Round 7
// baseline (426.649 us; speedup 1.0000x reference)
//
#include <hip/hip_runtime.h>
#include <hip/hip_cooperative_groups.h>
#include <stdint.h>

namespace cg = cooperative_groups;

#define N_Q 16384
#define M_P 1024
#define D_K 1024

typedef __attribute__((ext_vector_type(8))) __bf16 bf16x8;
typedef __attribute__((ext_vector_type(4))) float floatx4;
typedef __attribute__((ext_vector_type(4))) unsigned int uint4v;

#define AS1 __attribute__((address_space(1)))
#define AS3 __attribute__((address_space(3)))

__device__ __forceinline__ unsigned short f2bf(float f) {
    unsigned int u = __float_as_uint(f);
    u += 0x7fffu + ((u >> 16) & 1u);   // round-to-nearest-even
    return (unsigned short)(u >> 16);
}
__device__ __forceinline__ float bf2f(unsigned short h) {
    return __uint_as_float(((unsigned int)h) << 16);
}

// Split 8 fp32 (one k-chunk) -> packed bf16 hi (16B) + lo (16B).
__device__ __forceinline__ void split_chunk(floatx4 f0, floatx4 f1,
                                            uint4v* hi, uint4v* lo) {
    float e[8] = {f0.x, f0.y, f0.z, f0.w, f1.x, f1.y, f1.z, f1.w};
    unsigned int hb[4], lb[4];
#pragma unroll
    for (int p = 0; p < 4; ++p) {
        unsigned int u0 = __float_as_uint(e[2 * p]);
        unsigned int u1 = __float_as_uint(e[2 * p + 1]);
        hb[p] = __builtin_amdgcn_perm(u1, u0, 0x07060302);  // [u0>>16, u1>>16]
        float l0 = e[2 * p]     - __uint_as_float(u0 & 0xffff0000u);
        float l1 = e[2 * p + 1] - __uint_as_float(u1 & 0xffff0000u);
        lb[p] = __builtin_amdgcn_perm(__float_as_uint(l1), __float_as_uint(l0),
                                      0x07060302);
    }
    uint4v h = {hb[0], hb[1], hb[2], hb[3]};
    uint4v l = {lb[0], lb[1], lb[2], lb[3]};
    *hi = h;
    *lo = l;
}

// ---------------------------------------------------------------------------
// GEMM body (R13 schedule, VERBATIM -- best verified: 95.6us, MfmaUtil 45.5,
// 0 bank conflicts). R15's 32x32 shape swap REVERTED: it added 6.3M LDS
// bank conflicts (~4 cyc on every ds_read; mechanism unresolved without
// disasm) and cost +8us. R13 = counted-lgkm read-ahead (16 outstanding ds
// ops, hw cap), one barrier/step, vmcnt(4) discipline (0 only at t=30).
// Shared by the standalone kernel (fallback) and the fused coop kernel.
// ---------------------------------------------------------------------------
__device__ __forceinline__ void gemm_body(
    const float* __restrict__ query,
    const unsigned short* __restrict__ ph, const unsigned short* __restrict__ pl,
    const float* __restrict__ p2, float* __restrict__ out,
    unsigned short (*sAh)[16 * 512], unsigned short (*sAl)[16 * 512],
    unsigned short (*sBh)[16 * 512], unsigned short (*sBl)[16 * 512]) {
    const int tid = threadIdx.x;
    const int wave = tid >> 6;   // 0..7
    const int lane = tid & 63;
    const int wr = wave >> 2;    // 0..1: row half (128 rows)
    const int wc = wave & 3;     // 0..3: col quarter (64 cols)

    // XCD-aware: 8 chunks of 32 blocks; chunk = same col-tile, 32 row-tiles.
    const int b = blockIdx.x;            // 0..255
    const int v = (b & 7) * 32 + (b >> 3);
    const int colt = v >> 6;             // 0..3
    const int rowt = v & 63;             // 0..63
    const int row0 = rowt * 256;
    const int col0 = colt * 256;

    // B staging (R4-verified pre-swizzled source, linear gload_lds dest):
    const int rlB = lane >> 2;
    const int cioB = (lane & 3) ^ ((lane >> 3) & 3);
    const int halfB = wave >> 2;         // 0: hi, 1: lo
    const int sgB = wave & 3;
    const unsigned short* gB = (halfB ? pl : ph)
        + (size_t)(col0 + sgB * 64 + rlB) * D_K + cioB * 8;

    // A staging: wave covers rows wave*32..wave*32+31 (2 subtiles of 16).
    const int rlA = lane >> 2;          // 0..15
    const int cA = lane & 3;            // k-granule 0..3
    const AS1 float* gA = (const AS1 float*)query
        + (size_t)(row0 + wave * 32 + rlA) * D_K + cA * 8;
    const int wroff = (4 * rlA + (cA ^ ((rlA >> 1) & 3))) * 8;  // shorts

    // fragment read offsets (swizzle-matched, conflict-free, R4-verified)
    const int rsel = lane & 15;
    const int kq = lane >> 4;
    const int fragoff = (4 * rsel + (kq ^ ((rsel >> 1) & 3))) * 8;

    floatx4 zero = {0.0f, 0.0f, 0.0f, 0.0f};
    floatx4 acc[8][4];
#pragma unroll
    for (int i = 0; i < 8; ++i)
#pragma unroll
        for (int j = 0; j < 4; ++j) acc[i][j] = zero;

    floatx4 f0[2], f1[2];        // A prefetch regs (16 VGPR)
    bf16x8 bh[4], bl[4];         // B fragments (held one K-step)
    bf16x8 ah[2][2], al[2][2];   // A fragments, 2 reg-sets (read-ahead)

    auto issueA = [&](int kb) {
#pragma unroll
        for (int s = 0; s < 2; ++s) {
            const AS1 float* p = gA + (size_t)(s * 16) * D_K + kb;
            f0[s] = *(const AS1 floatx4*)p;
            f1[s] = *(const AS1 floatx4*)(p + 4);
        }
    };
    auto issueB = [&](int kb, int nxt) {
        unsigned short* dstB = (halfB ? sBl[nxt] : sBh[nxt]) + sgB * 4 * 512;
#pragma unroll
        for (int s = 0; s < 4; ++s)
            __builtin_amdgcn_global_load_lds(
                (const AS1 unsigned int*)(const void*)(gB + (size_t)(s * 16) * D_K + kb),
                (AS3 unsigned int*)(void*)(dstB + s * 512), 16, 0, 0);
    };
    auto writeA = [&](int nxt, int s) {
        uint4v hi, lo;
        split_chunk(f0[s], f1[s], &hi, &lo);
        const int off = (wave * 2 + s) * 512 + wroff;
        *(uint4v*)(sAh[nxt] + off) = hi;
        *(uint4v*)(sAl[nxt] + off) = lo;
    };
    auto ldBfrag = [&](int cur) {
#pragma unroll
        for (int j = 0; j < 4; ++j) {
            const int boff = (wc * 4 + j) * 512 + fragoff;
            bh[j] = *(const bf16x8*)(sBh[cur] + boff);
            bl[j] = *(const bf16x8*)(sBl[cur] + boff);
        }
    };
    auto ldA = [&](int cur, int i0, int set) {
#pragma unroll
        for (int t = 0; t < 2; ++t) {
            const int aoff = (wr * 8 + i0 + t) * 512 + fragoff;
            ah[set][t] = *(const bf16x8*)(sAh[cur] + aoff);
            al[set][t] = *(const bf16x8*)(sAl[cur] + aoff);
        }
    };
    auto mfma2 = [&](int i0, int set) {
#pragma unroll
        for (int j = 0; j < 4; ++j)
#pragma unroll
            for (int t = 0; t < 2; ++t) {
                acc[i0 + t][j] = __builtin_amdgcn_mfma_f32_16x16x32_bf16(ah[set][t], bh[j], acc[i0 + t][j], 0, 0, 0);
                acc[i0 + t][j] = __builtin_amdgcn_mfma_f32_16x16x32_bf16(ah[set][t], bl[j], acc[i0 + t][j], 0, 0, 0);
                acc[i0 + t][j] = __builtin_amdgcn_mfma_f32_16x16x32_bf16(al[set][t], bh[j], acc[i0 + t][j], 0, 0, 0);
            }
    };

#define LGKM_MFMA(n, i0, set)                                   \
    asm volatile("s_waitcnt lgkmcnt(" #n ")" ::: "memory");     \
    __builtin_amdgcn_sched_barrier(0);                          \
    __builtin_amdgcn_s_setprio(1);                              \
    mfma2(i0, set);                                             \
    __builtin_amdgcn_s_setprio(0);

    auto stepf = [&](int kbB, int kbA, int cur, int nxt, bool pfB, bool pfA) {
        if (pfB) issueB(kbB, nxt);
        ldBfrag(cur);                // 8 reads
        ldA(cur, 0, 0);              // 4 reads
        ldA(cur, 2, 1);              // 4 reads   [16 outstanding, hw cap]
        LGKM_MFMA(4, 0, 0)           // B+A01 done; A23 in flight under MFMA
        ldA(cur, 4, 0);
        LGKM_MFMA(4, 2, 1)           // A23 done; A45 in flight under MFMA
        ldA(cur, 6, 1);
        LGKM_MFMA(4, 4, 0)           // A45 done; A67 in flight under MFMA
        if (pfB) { writeA(nxt, 0); writeA(nxt, 1); }  // VALU + 4 ds_write
        if (pfA) issueA(kbA);        // f-regs free after split VALU
        if (pfB) { asm volatile("s_waitcnt lgkmcnt(4)" ::: "memory"); }
        else     { asm volatile("s_waitcnt lgkmcnt(0)" ::: "memory"); }
        __builtin_amdgcn_sched_barrier(0);
        __builtin_amdgcn_s_setprio(1);
        mfma2(6, 1);
        __builtin_amdgcn_s_setprio(0);
        asm volatile("s_waitcnt lgkmcnt(0)" ::: "memory");  // ds_writes drained
        if (pfB) {
            if (pfA) { asm volatile("s_waitcnt vmcnt(4)" ::: "memory"); }
            else     { asm volatile("s_waitcnt vmcnt(0)" ::: "memory"); }
        }
        __builtin_amdgcn_s_barrier();   // the ONE barrier per step
    };

    // prologue: tile 0 -> buf0; prefetch A(t1).
    issueA(0);
    issueB(0, 0);
    writeA(0, 0);
    writeA(0, 1);
    issueA(32);
    asm volatile("s_waitcnt lgkmcnt(0)" ::: "memory");
    asm volatile("s_waitcnt vmcnt(4)" ::: "memory");   // B(t0) landed
    __builtin_amdgcn_s_barrier();

    for (int kt = 0; kt < 30; kt += 2) {
        stepf((kt + 1) * 32, (kt + 2) * 32, 0, 1, true, true);
        stepf((kt + 2) * 32, (kt + 3) * 32, 1, 0, true, true);
    }
    stepf(31 * 32, 0, 0, 1, true, false);   // t=30: stage t31, drain vmcnt(0)
    stepf(0, 0, 1, 0, false, false);        // t=31: compute only

#undef LGKM_MFMA

    // ---- epilogue: logits = 2*qp - p2[col] ----
    // C layout (verified m89/m91): col = lane&15, row = (lane>>4)*4 + reg
#pragma unroll
    for (int j = 0; j < 4; ++j) {
        const int gc = col0 + wc * 64 + j * 16 + rsel;
        const float p2v = p2[gc];
#pragma unroll
        for (int i = 0; i < 8; ++i) {
            const int gr = row0 + wr * 128 + i * 16 + kq * 4;
#pragma unroll
            for (int r = 0; r < 4; ++r) {
                out[(size_t)(gr + r) * M_P + gc] = 2.0f * acc[i][j][r] - p2v;
            }
        }
    }
}

// ---------------------------------------------------------------------------
// Wave-per-row softmax body (one row per wave, 1024 cols).
// ---------------------------------------------------------------------------
__device__ __forceinline__ void softmax_row(float* __restrict__ row, int lane) {
    floatx4 v[4];
#pragma unroll
    for (int k = 0; k < 4; ++k)
        v[k] = *((const floatx4*)row + k * 64 + lane);
    float mx = fmaxf(fmaxf(v[0].x, v[0].y), fmaxf(v[0].z, v[0].w));
#pragma unroll
    for (int k = 1; k < 4; ++k)
        mx = fmaxf(mx, fmaxf(fmaxf(v[k].x, v[k].y), fmaxf(v[k].z, v[k].w)));
#pragma unroll
    for (int off = 1; off < 64; off <<= 1) mx = fmaxf(mx, __shfl_xor(mx, off));
    float s = 0.0f;
#pragma unroll
    for (int k = 0; k < 4; ++k) {
        v[k].x = __expf(v[k].x - mx);
        v[k].y = __expf(v[k].y - mx);
        v[k].z = __expf(v[k].z - mx);
        v[k].w = __expf(v[k].w - mx);
        s += v[k].x + v[k].y + v[k].z + v[k].w;
    }
#pragma unroll
    for (int off = 1; off < 64; off <<= 1) s += __shfl_xor(s, off);
    const float inv = 1.0f / s;
#pragma unroll
    for (int k = 0; k < 4; ++k) {
        floatx4 o;
        o.x = v[k].x * inv; o.y = v[k].y * inv;
        o.z = v[k].z * inv; o.w = v[k].w * inv;
        __builtin_nontemporal_store(o, (floatx4*)row + k * 64 + lane);
    }
}

// ---------------------------------------------------------------------------
// FUSED cooperative kernel: convert | grid.sync | gemm | grid.sync | softmax.
// Grid = 256 blocks x 512 thr, 128KB LDS -> exactly 1 block/CU co-resident
// (the validated coop regime). Removes 2 inter-kernel launch gaps from the
// graph. Cross-phase visibility: __threadfence (device-scope) + grid.sync
// (G16: per-XCD L2 non-coherence).
// ---------------------------------------------------------------------------
__global__ __launch_bounds__(512, 2) void fused_kernel(
    const float* __restrict__ query, const float* __restrict__ proto,
    unsigned short* __restrict__ ph, unsigned short* __restrict__ pl,
    float* __restrict__ p2, float* __restrict__ out) {
    __shared__ unsigned short sAh[2][16 * 512];   // 2 x 16 KB
    __shared__ unsigned short sAl[2][16 * 512];
    __shared__ unsigned short sBh[2][16 * 512];
    __shared__ unsigned short sBl[2][16 * 512];   // 128 KB total
    __shared__ float sred[8];

    const int tid = threadIdx.x;

    // ---- Phase 1: proto convert (4 rows/block, 128 thr/row, 8 f32/thr) ----
    {
        const int r = blockIdx.x * 4 + (tid >> 7);
        const int c = tid & 127;
        const size_t base4 = (size_t)r * (D_K / 4) + c * 2;
        const float4 v0 = ((const float4*)proto)[base4];
        const float4 v1 = ((const float4*)proto)[base4 + 1];
        ushort4 h0, l0, h1, l1;
        h0.x = f2bf(v0.x); l0.x = f2bf(v0.x - bf2f(h0.x));
        h0.y = f2bf(v0.y); l0.y = f2bf(v0.y - bf2f(h0.y));
        h0.z = f2bf(v0.z); l0.z = f2bf(v0.z - bf2f(h0.z));
        h0.w = f2bf(v0.w); l0.w = f2bf(v0.w - bf2f(h0.w));
        h1.x = f2bf(v1.x); l1.x = f2bf(v1.x - bf2f(h1.x));
        h1.y = f2bf(v1.y); l1.y = f2bf(v1.y - bf2f(h1.y));
        h1.z = f2bf(v1.z); l1.z = f2bf(v1.z - bf2f(h1.z));
        h1.w = f2bf(v1.w); l1.w = f2bf(v1.w - bf2f(h1.w));
        ((ushort4*)ph)[base4] = h0; ((ushort4*)ph)[base4 + 1] = h1;
        ((ushort4*)pl)[base4] = l0; ((ushort4*)pl)[base4 + 1] = l1;
        float sq = v0.x * v0.x + v0.y * v0.y + v0.z * v0.z + v0.w * v0.w
                 + v1.x * v1.x + v1.y * v1.y + v1.z * v1.z + v1.w * v1.w;
#pragma unroll
        for (int off = 1; off < 64; off <<= 1) sq += __shfl_xor(sq, off);
        if ((tid & 63) == 0) sred[tid >> 6] = sq;   // wave w covers row w>>1
        __syncthreads();
        if (tid < 4) p2[blockIdx.x * 4 + tid] = sred[2 * tid] + sred[2 * tid + 1];
    }
    __threadfence();
    cg::this_grid().sync();
    __threadfence();

    // ---- Phase 2: GEMM (R13 verbatim) ----
    gemm_body(query, ph, pl, p2, out, sAh, sAl, sBh, sBl);

    __threadfence();
    cg::this_grid().sync();
    __threadfence();

    // ---- Phase 3: softmax (64 rows/block, wave-per-row x 8 iters) ----
    {
        const int lane = tid & 63;
        const int w = tid >> 6;
#pragma unroll
        for (int it = 0; it < 8; ++it) {
            const int n = blockIdx.x * 64 + it * 8 + w;
            softmax_row(out + (size_t)n * M_P, lane);
        }
    }
}

// ---------------------------------------------------------------------------
// Standalone kernels (fallback path if cooperative launch is unavailable).
// ---------------------------------------------------------------------------
__global__ __launch_bounds__(256) void convert_proto_kernel(
    const float* __restrict__ proto, unsigned short* __restrict__ ph,
    unsigned short* __restrict__ pl, float* __restrict__ p2) {
    __shared__ float sred[4];
    int m = blockIdx.x;
    int t = threadIdx.x;
    size_t base4 = (size_t)m * (D_K / 4) + t;
    float4 v = ((const float4*)proto)[base4];
    ushort4 h, l;
    h.x = f2bf(v.x); l.x = f2bf(v.x - bf2f(h.x));
    h.y = f2bf(v.y); l.y = f2bf(v.y - bf2f(h.y));
    h.z = f2bf(v.z); l.z = f2bf(v.z - bf2f(h.z));
    h.w = f2bf(v.w); l.w = f2bf(v.w - bf2f(h.w));
    ((ushort4*)ph)[base4] = h;
    ((ushort4*)pl)[base4] = l;
    float sq = v.x * v.x + v.y * v.y + v.z * v.z + v.w * v.w;
#pragma unroll
    for (int off = 1; off < 64; off <<= 1) sq += __shfl_xor(sq, off);
    if ((t & 63) == 0) sred[t >> 6] = sq;
    __syncthreads();
    if (t == 0) p2[m] = sred[0] + sred[1] + sred[2] + sred[3];
}

__global__ __launch_bounds__(512, 2) void gemm_logits_kernel(
    const float* __restrict__ query,
    const unsigned short* __restrict__ ph, const unsigned short* __restrict__ pl,
    const float* __restrict__ p2, float* __restrict__ out) {
    __shared__ unsigned short sAh[2][16 * 512];
    __shared__ unsigned short sAl[2][16 * 512];
    __shared__ unsigned short sBh[2][16 * 512];
    __shared__ unsigned short sBl[2][16 * 512];
    gemm_body(query, ph, pl, p2, out, sAh, sAl, sBh, sBl);
}

__global__ __launch_bounds__(256) void softmax_kernel(float* __restrict__ out) {
    const int lane = threadIdx.x & 63;
    int n = blockIdx.x * 4 + (threadIdx.x >> 6);
    for (int it = 0; it < 2; ++it, n += 8192) {
        softmax_row(out + (size_t)n * M_P, lane);
    }
}

__global__ __launch_bounds__(256) void naive_logits_kernel(
    const float* __restrict__ query, const float* __restrict__ proto,
    float* __restrict__ out) {
    __shared__ float qs[D_K];
    int n = blockIdx.x;
    int t = threadIdx.x;
    ((float4*)qs)[t] = ((const float4*)(query + (size_t)n * D_K))[t];
    __syncthreads();
    float acc[4] = {0.f, 0.f, 0.f, 0.f};
    float pp[4] = {0.f, 0.f, 0.f, 0.f};
    for (int d = 0; d < D_K; d += 4) {
        float4 qv = *(const float4*)(qs + d);
#pragma unroll
        for (int j = 0; j < 4; ++j) {
            const float4 pv = *(const float4*)(proto + (size_t)(t + 256 * j) * D_K + d);
            acc[j] += qv.x * pv.x + qv.y * pv.y + qv.z * pv.z + qv.w * pv.w;
            pp[j] += pv.x * pv.x + pv.y * pv.y + pv.z * pv.z + pv.w * pv.w;
        }
    }
#pragma unroll
    for (int j = 0; j < 4; ++j)
        out[(size_t)n * M_P + t + 256 * j] = 2.0f * acc[j] - pp[j];
}

extern "C" void kernel_launch(void* const* d_in, const int* in_sizes, int n_in,
                              void* d_out, int out_size, void* d_ws, size_t ws_size,
                              hipStream_t stream) {
    const float* query = (const float*)d_in[0];
    const float* proto = (const float*)d_in[1];
    float* out = (float*)d_out;

    const size_t pElems = (size_t)M_P * D_K;   // 1M
    const size_t needed = pElems * 2 * 2 + M_P * 4;  // ~4.2 MiB

    if (ws_size >= needed) {
        unsigned short* ph = (unsigned short*)d_ws;
        unsigned short* pl = ph + pElems;
        float* p2 = (float*)(pl + pElems);

        // Try the fused cooperative launch (1 dispatch, 2 grid syncs).
        void* args[] = {(void*)&query, (void*)&proto, (void*)&ph,
                        (void*)&pl,    (void*)&p2,    (void*)&out};
        hipError_t e = hipLaunchCooperativeKernel(
            (const void*)fused_kernel, dim3(256), dim3(512), args, 0, stream);
        if (e != hipSuccess) {
            // Fallback: proven 3-kernel R13 sequence.
            convert_proto_kernel<<<M_P, 256, 0, stream>>>(proto, ph, pl, p2);
            gemm_logits_kernel<<<(N_Q / 256) * (M_P / 256), 512, 0, stream>>>(
                query, ph, pl, p2, out);
            softmax_kernel<<<N_Q / 8, 256, 0, stream>>>(out);
        }
    } else {
        naive_logits_kernel<<<N_Q, 256, 0, stream>>>(query, proto, out);
        softmax_kernel<<<N_Q / 8, 256, 0, stream>>>(out);
    }
}

// Round 8
// 222.219 us; speedup vs baseline: 1.9199x; 1.9199x over previous
//
#include <hip/hip_runtime.h>
#include <stdint.h>

#define N_Q 16384
#define M_P 1024
#define D_K 1024

typedef __attribute__((ext_vector_type(8))) __bf16 bf16x8;
typedef __attribute__((ext_vector_type(4))) float floatx4;
typedef __attribute__((ext_vector_type(4))) unsigned int uint4v;

#define AS1 __attribute__((address_space(1)))
#define AS3 __attribute__((address_space(3)))

__device__ __forceinline__ unsigned short f2bf(float f) {
    unsigned int u = __float_as_uint(f);
    u += 0x7fffu + ((u >> 16) & 1u);   // round-to-nearest-even
    return (unsigned short)(u >> 16);
}
__device__ __forceinline__ float bf2f(unsigned short h) {
    return __uint_as_float(((unsigned int)h) << 16);
}

// Split 8 fp32 (one k-chunk) -> packed bf16 hi (16B) + lo (16B).
__device__ __forceinline__ void split_chunk(floatx4 f0, floatx4 f1,
                                            uint4v* hi, uint4v* lo) {
    float e[8] = {f0.x, f0.y, f0.z, f0.w, f1.x, f1.y, f1.z, f1.w};
    unsigned int hb[4], lb[4];
#pragma unroll
    for (int p = 0; p < 4; ++p) {
        unsigned int u0 = __float_as_uint(e[2 * p]);
        unsigned int u1 = __float_as_uint(e[2 * p + 1]);
        hb[p] = __builtin_amdgcn_perm(u1, u0, 0x07060302);  // [u0>>16, u1>>16]
        float l0 = e[2 * p]     - __uint_as_float(u0 & 0xffff0000u);
        float l1 = e[2 * p + 1] - __uint_as_float(u1 & 0xffff0000u);
        lb[p] = __builtin_amdgcn_perm(__float_as_uint(l1), __float_as_uint(l0),
                                      0x07060302);
    }
    uint4v h = {hb[0], hb[1], hb[2], hb[3]};
    uint4v l = {lb[0], lb[1], lb[2], lb[3]};
    *hi = h;
    *lo = l;
}

// ---------------------------------------------------------------------------
// Proto convert: split fp32 -> bf16 hi/lo + p2[m]. One block per row. ~5 us.
// ---------------------------------------------------------------------------
__global__ __launch_bounds__(256) void convert_proto_kernel(
    const float* __restrict__ proto, unsigned short* __restrict__ ph,
    unsigned short* __restrict__ pl, float* __restrict__ p2) {
    __shared__ float sred[4];
    int m = blockIdx.x;
    int t = threadIdx.x;
    size_t base4 = (size_t)m * (D_K / 4) + t;
    float4 v = ((const float4*)proto)[base4];
    ushort4 h, l;
    h.x = f2bf(v.x); l.x = f2bf(v.x - bf2f(h.x));
    h.y = f2bf(v.y); l.y = f2bf(v.y - bf2f(h.y));
    h.z = f2bf(v.z); l.z = f2bf(v.z - bf2f(h.z));
    h.w = f2bf(v.w); l.w = f2bf(v.w - bf2f(h.w));
    ((ushort4*)ph)[base4] = h;
    ((ushort4*)pl)[base4] = l;
    float sq = v.x * v.x + v.y * v.y + v.z * v.z + v.w * v.w;
#pragma unroll
    for (int off = 1; off < 64; off <<= 1) sq += __shfl_xor(sq, off);
    if ((t & 63) == 0) sred[t >> 6] = sq;
    __syncthreads();
    if (t == 0) p2[m] = sred[0] + sred[1] + sred[2] + sred[3];
}

// ---------------------------------------------------------------------------
// GEMM: logits[n,m] = 2*sum_d q[n,d]*p[m,d] - p2[m], bf16 hi/lo 3-term.
//
// R18: R13 schedule VERBATIM, tile 256x256 -> 128x128 => LDS 64KB =>
// 2 blocks/CU (16 waves/CU). R16/R17 post-mortem: coop fusion added ~200us
// of grid.sync idle (reverted); R13's residual gap is latency + the
// epilogue store burst with NO co-resident block to cover it (1 block/CU).
// m114: inter-block overlap is what covers barrier/epilogue stalls; the
// m97 ladder's 128^2 tile ran at 2-3 blocks/CU.
// Per-step counts halved from R13: B 2 gload_lds, A 1 chunk (2 loads,
// 1 split, 2 ds_writes), 12 ds_reads, 4 MFMA clusters x 6.
// Counted waits re-derived: lgkm(2) per phase (reads-only FIFO),
// end-of-step vmcnt(2) [B(t+1) landed, A(t+2) in flight], vmcnt(0) only
// at t=30. Grid 1024 blocks = 2 residency rounds (round 2 covers round
// 1's epilogue tails). XCD: colt=b&7 -> one 512KB B-panel per XCD
// (L2-resident); A panels via L3 (64MB, L3-resident).
// Swizzles / split numerics / per-output 3-term order bit-identical to
// R13 -> absmax must stay exactly 0.00390625.
// ---------------------------------------------------------------------------
__global__ __launch_bounds__(512, 4) void gemm_logits_kernel(
    const float* __restrict__ query,
    const unsigned short* __restrict__ ph, const unsigned short* __restrict__ pl,
    const float* __restrict__ p2, float* __restrict__ out) {
    __shared__ unsigned short sAh[2][8 * 512];   // 2 x 8 KB
    __shared__ unsigned short sAl[2][8 * 512];   // 2 x 8 KB
    __shared__ unsigned short sBh[2][8 * 512];   // 2 x 8 KB
    __shared__ unsigned short sBl[2][8 * 512];   // 2 x 8 KB  (64 KB)

    const int tid = threadIdx.x;
    const int wave = tid >> 6;   // 0..7
    const int lane = tid & 63;
    const int wr = wave >> 2;    // 0..1: row half (64 rows)
    const int wc = wave & 3;     // 0..3: col quarter (32 cols)

    // XCD-aware: colt = b&7 -> all blocks of one col-tile on one XCD
    // (B panel 512KB stays L2-resident there).
    const int b = blockIdx.x;            // 0..1023
    const int colt = b & 7;              // 0..7
    const int rowt = b >> 3;             // 0..127
    const int row0 = rowt * 128;
    const int col0 = colt * 128;

    // B staging (R4-verified pre-swizzled source, linear gload_lds dest):
    // wave (halfB, sgB): halfB 0=hi 1=lo; sgB covers rows sgB*32..+31
    // (subtiles 2*sgB, 2*sgB+1), 2 gload_lds per thread per step.
    const int rlB = lane >> 2;
    const int cioB = (lane & 3) ^ ((lane >> 3) & 3);
    const int halfB = wave >> 2;         // 0: hi, 1: lo
    const int sgB = wave & 3;
    const unsigned short* gB = (halfB ? pl : ph)
        + (size_t)(col0 + sgB * 32 + rlB) * D_K + cioB * 8;

    // A staging: wave w covers rows w*16..w*16+15 (1 subtile), 1 chunk/thr.
    const int rlA = lane >> 2;          // 0..15
    const int cA = lane & 3;            // k-granule 0..3
    const AS1 float* gA = (const AS1 float*)query
        + (size_t)(row0 + wave * 16 + rlA) * D_K + cA * 8;
    const int wroff = (4 * rlA + (cA ^ ((rlA >> 1) & 3))) * 8;  // shorts

    // fragment read offsets (swizzle-matched, conflict-free, R4-verified)
    const int rsel = lane & 15;
    const int kq = lane >> 4;
    const int fragoff = (4 * rsel + (kq ^ ((rsel >> 1) & 3))) * 8;

    floatx4 zero = {0.0f, 0.0f, 0.0f, 0.0f};
    floatx4 acc[4][2];
#pragma unroll
    for (int i = 0; i < 4; ++i)
#pragma unroll
        for (int j = 0; j < 2; ++j) acc[i][j] = zero;

    floatx4 f0, f1;              // A prefetch regs (8 VGPR)
    bf16x8 bh[2], bl[2];         // B fragments (held one K-step)
    bf16x8 ah[2], al[2];         // A fragments, 2 reg-sets (read-ahead)

    auto issueA = [&](int kb) {
        const AS1 float* p = gA + kb;
        f0 = *(const AS1 floatx4*)p;
        f1 = *(const AS1 floatx4*)(p + 4);
    };
    auto issueB = [&](int kb, int nxt) {
        unsigned short* dstB = (halfB ? sBl[nxt] : sBh[nxt]) + sgB * 2 * 512;
#pragma unroll
        for (int s = 0; s < 2; ++s)
            __builtin_amdgcn_global_load_lds(
                (const AS1 unsigned int*)(const void*)(gB + (size_t)(s * 16) * D_K + kb),
                (AS3 unsigned int*)(void*)(dstB + s * 512), 16, 0, 0);
    };
    auto writeA = [&](int nxt) {
        uint4v hi, lo;
        split_chunk(f0, f1, &hi, &lo);
        const int off = wave * 512 + wroff;
        *(uint4v*)(sAh[nxt] + off) = hi;
        *(uint4v*)(sAl[nxt] + off) = lo;
    };
    auto ldBfrag = [&](int cur) {
#pragma unroll
        for (int j = 0; j < 2; ++j) {
            const int boff = (wc * 2 + j) * 512 + fragoff;
            bh[j] = *(const bf16x8*)(sBh[cur] + boff);
            bl[j] = *(const bf16x8*)(sBl[cur] + boff);
        }
    };
    // load A-frag for row-tile i into reg-set `set` (literal at all sites)
    auto ldA = [&](int cur, int i, int set) {
        const int aoff = (wr * 4 + i) * 512 + fragoff;
        ah[set] = *(const bf16x8*)(sAh[cur] + aoff);
        al[set] = *(const bf16x8*)(sAl[cur] + aoff);
    };
    // one cluster: row-tile i x 2 col-tiles x 3 terms = 6 MFMA
    auto mfmaC = [&](int i, int set) {
#pragma unroll
        for (int j = 0; j < 2; ++j) {
            acc[i][j] = __builtin_amdgcn_mfma_f32_16x16x32_bf16(ah[set], bh[j], acc[i][j], 0, 0, 0);
            acc[i][j] = __builtin_amdgcn_mfma_f32_16x16x32_bf16(ah[set], bl[j], acc[i][j], 0, 0, 0);
            acc[i][j] = __builtin_amdgcn_mfma_f32_16x16x32_bf16(al[set], bh[j], acc[i][j], 0, 0, 0);
        }
    };

#define LGKM_MFMA(n, i, set)                                    \
    asm volatile("s_waitcnt lgkmcnt(" #n ")" ::: "memory");     \
    __builtin_amdgcn_sched_barrier(0);                          \
    __builtin_amdgcn_s_setprio(1);                              \
    mfmaC(i, set);                                              \
    __builtin_amdgcn_s_setprio(0);

    // One K-step t. DS order: [B 4r][A0 2r][A1 2r] |2| [A2 2r] |2|
    // [A3 2r] |2| [W 2w] |2| cluster3 | lgkm(0).
    // Vmem order: [B(t+1) x2][A(t+2) x2]; end-of-step vmcnt(2).
    auto stepf = [&](int kbB, int kbA, int cur, int nxt, bool pfB, bool pfA) {
        if (pfB) issueB(kbB, nxt);
        ldBfrag(cur);                // 4 reads
        ldA(cur, 0, 0);              // 2 reads
        ldA(cur, 1, 1);              // 2 reads   [8 outstanding]
        LGKM_MFMA(2, 0, 0)           // B+A0 done; A1 in flight under MFMA
        ldA(cur, 2, 0);
        LGKM_MFMA(2, 1, 1)           // A1 done; A2 in flight under MFMA
        ldA(cur, 3, 1);
        LGKM_MFMA(2, 2, 0)           // A2 done; A3 in flight under MFMA
        if (pfB) writeA(nxt);        // split VALU + 2 ds_write
        if (pfA) issueA(kbA);        // f-regs free after split
        if (pfB) { asm volatile("s_waitcnt lgkmcnt(2)" ::: "memory"); }
        else     { asm volatile("s_waitcnt lgkmcnt(0)" ::: "memory"); }
        __builtin_amdgcn_sched_barrier(0);
        __builtin_amdgcn_s_setprio(1);
        mfmaC(3, 1);
        __builtin_amdgcn_s_setprio(0);
        asm volatile("s_waitcnt lgkmcnt(0)" ::: "memory");  // ds_writes drained
        if (pfB) {
            if (pfA) { asm volatile("s_waitcnt vmcnt(2)" ::: "memory"); }
            else     { asm volatile("s_waitcnt vmcnt(0)" ::: "memory"); }
        }
        __builtin_amdgcn_s_barrier();   // the ONE barrier per step
    };

    // prologue: tile 0 -> buf0; prefetch A(t1).
    issueA(0);                  // A(t0): oldest 2 vmem
    issueB(0, 0);               // B(t0): next 2
    writeA(0);                  // compiler waits vmcnt(2): A(t0) done, B in flight
    issueA(32);                 // A(t1) in flight across the barrier
    asm volatile("s_waitcnt lgkmcnt(0)" ::: "memory");
    asm volatile("s_waitcnt vmcnt(2)" ::: "memory");   // B(t0) landed
    __builtin_amdgcn_s_barrier();

    for (int kt = 0; kt < 30; kt += 2) {
        stepf((kt + 1) * 32, (kt + 2) * 32, 0, 1, true, true);
        stepf((kt + 2) * 32, (kt + 3) * 32, 1, 0, true, true);
    }
    stepf(31 * 32, 0, 0, 1, true, false);   // t=30: stage t31, drain vmcnt(0)
    stepf(0, 0, 1, 0, false, false);        // t=31: compute only

#undef LGKM_MFMA

    // ---- epilogue: logits = 2*qp - p2[col] ----
    // C layout (verified m89/m91): col = lane&15, row = (lane>>4)*4 + reg
#pragma unroll
    for (int j = 0; j < 2; ++j) {
        const int gc = col0 + wc * 32 + j * 16 + rsel;
        const float p2v = p2[gc];
#pragma unroll
        for (int i = 0; i < 4; ++i) {
            const int gr = row0 + wr * 64 + i * 16 + kq * 4;
#pragma unroll
            for (int r = 0; r < 4; ++r) {
                out[(size_t)(gr + r) * M_P + gc] = 2.0f * acc[i][j][r] - p2v;
            }
        }
    }
}

// ---------------------------------------------------------------------------
// Fallback (tiny workspace): naive fp32 logits + separate softmax.
// ---------------------------------------------------------------------------
__global__ __launch_bounds__(256) void naive_logits_kernel(
    const float* __restrict__ query, const float* __restrict__ proto,
    float* __restrict__ out) {
    __shared__ float qs[D_K];
    int n = blockIdx.x;
    int t = threadIdx.x;
    ((float4*)qs)[t] = ((const float4*)(query + (size_t)n * D_K))[t];
    __syncthreads();
    float acc[4] = {0.f, 0.f, 0.f, 0.f};
    float pp[4] = {0.f, 0.f, 0.f, 0.f};
    for (int d = 0; d < D_K; d += 4) {
        float4 qv = *(const float4*)(qs + d);
#pragma unroll
        for (int j = 0; j < 4; ++j) {
            const float4 pv = *(const float4*)(proto + (size_t)(t + 256 * j) * D_K + d);
            acc[j] += qv.x * pv.x + qv.y * pv.y + qv.z * pv.z + qv.w * pv.w;
            pp[j] += pv.x * pv.x + pv.y * pv.y + pv.z * pv.z + pv.w * pv.w;
        }
    }
#pragma unroll
    for (int j = 0; j < 4; ++j)
        out[(size_t)n * M_P + t + 256 * j] = 2.0f * acc[j] - pp[j];
}

// ---------------------------------------------------------------------------
// In-place row softmax, wave-per-row (no LDS/barriers). ~24 us measured.
// ---------------------------------------------------------------------------
__global__ __launch_bounds__(256) void softmax_kernel(float* __restrict__ out) {
    const int lane = threadIdx.x & 63;
    int n = blockIdx.x * 4 + (threadIdx.x >> 6);
    for (int it = 0; it < 2; ++it, n += 8192) {
        float* row = out + (size_t)n * M_P;
        floatx4 v[4];
#pragma unroll
        for (int k = 0; k < 4; ++k)
            v[k] = *((const floatx4*)row + k * 64 + lane);
        float mx = fmaxf(fmaxf(v[0].x, v[0].y), fmaxf(v[0].z, v[0].w));
#pragma unroll
        for (int k = 1; k < 4; ++k)
            mx = fmaxf(mx, fmaxf(fmaxf(v[k].x, v[k].y), fmaxf(v[k].z, v[k].w)));
#pragma unroll
        for (int off = 1; off < 64; off <<= 1) mx = fmaxf(mx, __shfl_xor(mx, off));
        float s = 0.0f;
#pragma unroll
        for (int k = 0; k < 4; ++k) {
            v[k].x = __expf(v[k].x - mx);
            v[k].y = __expf(v[k].y - mx);
            v[k].z = __expf(v[k].z - mx);
            v[k].w = __expf(v[k].w - mx);
            s += v[k].x + v[k].y + v[k].z + v[k].w;
        }
#pragma unroll
        for (int off = 1; off < 64; off <<= 1) s += __shfl_xor(s, off);
        const float inv = 1.0f / s;
#pragma unroll
        for (int k = 0; k < 4; ++k) {
            floatx4 o;
            o.x = v[k].x * inv; o.y = v[k].y * inv;
            o.z = v[k].z * inv; o.w = v[k].w * inv;
            __builtin_nontemporal_store(o, (floatx4*)row + k * 64 + lane);
        }
    }
}

extern "C" void kernel_launch(void* const* d_in, const int* in_sizes, int n_in,
                              void* d_out, int out_size, void* d_ws, size_t ws_size,
                              hipStream_t stream) {
    const float* query = (const float*)d_in[0];
    const float* proto = (const float*)d_in[1];
    float* out = (float*)d_out;

    const size_t pElems = (size_t)M_P * D_K;   // 1M
    const size_t needed = pElems * 2 * 2 + M_P * 4;  // ~4.2 MiB

    if (ws_size >= needed) {
        unsigned short* ph = (unsigned short*)d_ws;
        unsigned short* pl = ph + pElems;
        float* p2 = (float*)(pl + pElems);

        convert_proto_kernel<<<M_P, 256, 0, stream>>>(proto, ph, pl, p2);
        gemm_logits_kernel<<<(N_Q / 128) * (M_P / 128), 512, 0, stream>>>(
            query, ph, pl, p2, out);
    } else {
        naive_logits_kernel<<<N_Q, 256, 0, stream>>>(query, proto, out);
    }
    softmax_kernel<<<2048, 256, 0, stream>>>(out);
}

// Round 9
// 204.751 us; speedup vs baseline: 2.0838x; 1.0853x over previous
//
#include <hip/hip_runtime.h>
#include <stdint.h>

#define N_Q 16384
#define M_P 1024
#define D_K 1024

typedef __attribute__((ext_vector_type(8))) __bf16 bf16x8;
typedef __attribute__((ext_vector_type(4))) float floatx4;
typedef __attribute__((ext_vector_type(4))) unsigned int uint4v;

#define AS1 __attribute__((address_space(1)))
#define AS3 __attribute__((address_space(3)))

__device__ __forceinline__ unsigned short f2bf(float f) {
    unsigned int u = __float_as_uint(f);
    u += 0x7fffu + ((u >> 16) & 1u);   // round-to-nearest-even
    return (unsigned short)(u >> 16);
}
__device__ __forceinline__ float bf2f(unsigned short h) {
    return __uint_as_float(((unsigned int)h) << 16);
}

// Split 8 fp32 (one k-chunk) -> packed bf16 hi (16B) + lo (16B).
__device__ __forceinline__ void split_chunk(floatx4 f0, floatx4 f1,
                                            uint4v* hi, uint4v* lo) {
    float e[8] = {f0.x, f0.y, f0.z, f0.w, f1.x, f1.y, f1.z, f1.w};
    unsigned int hb[4], lb[4];
#pragma unroll
    for (int p = 0; p < 4; ++p) {
        unsigned int u0 = __float_as_uint(e[2 * p]);
        unsigned int u1 = __float_as_uint(e[2 * p + 1]);
        hb[p] = __builtin_amdgcn_perm(u1, u0, 0x07060302);  // [u0>>16, u1>>16]
        float l0 = e[2 * p]     - __uint_as_float(u0 & 0xffff0000u);
        float l1 = e[2 * p + 1] - __uint_as_float(u1 & 0xffff0000u);
        lb[p] = __builtin_amdgcn_perm(__float_as_uint(l1), __float_as_uint(l0),
                                      0x07060302);
    }
    uint4v h = {hb[0], hb[1], hb[2], hb[3]};
    uint4v l = {lb[0], lb[1], lb[2], lb[3]};
    *hi = h;
    *lo = l;
}

// ---------------------------------------------------------------------------
// Proto convert: split fp32 -> bf16 hi/lo + p2[m]. One block per row. ~5 us.
// ---------------------------------------------------------------------------
__global__ __launch_bounds__(256) void convert_proto_kernel(
    const float* __restrict__ proto, unsigned short* __restrict__ ph,
    unsigned short* __restrict__ pl, float* __restrict__ p2) {
    __shared__ float sred[4];
    int m = blockIdx.x;
    int t = threadIdx.x;
    size_t base4 = (size_t)m * (D_K / 4) + t;
    float4 v = ((const float4*)proto)[base4];
    ushort4 h, l;
    h.x = f2bf(v.x); l.x = f2bf(v.x - bf2f(h.x));
    h.y = f2bf(v.y); l.y = f2bf(v.y - bf2f(h.y));
    h.z = f2bf(v.z); l.z = f2bf(v.z - bf2f(h.z));
    h.w = f2bf(v.w); l.w = f2bf(v.w - bf2f(h.w));
    ((ushort4*)ph)[base4] = h;
    ((ushort4*)pl)[base4] = l;
    float sq = v.x * v.x + v.y * v.y + v.z * v.z + v.w * v.w;
#pragma unroll
    for (int off = 1; off < 64; off <<= 1) sq += __shfl_xor(sq, off);
    if ((t & 63) == 0) sred[t >> 6] = sq;
    __syncthreads();
    if (t == 0) p2[m] = sred[0] + sred[1] + sred[2] + sred[3];
}

// ---------------------------------------------------------------------------
// GEMM: logits[n,m] = 2*sum_d q[n,d]*p[m,d] - p2[m], bf16 hi/lo 3-term.
//
// R19 = R13 EXACT REVERT (best verified: 95.6us gemm, MfmaUtil 45.5,
// 0 bank conflicts, total 196.7-198.1). Plateau record -- challengers all
// lost: R14 triple-buffer B (+0%, 160KB LDS cold-dispatch hazard),
// R15 32x32 MFMA (-8%: +6.3M LDS bank conflicts), R16 coop fusion
// (-130%: grid.sync convoy ~200us idle), R18 128^2 tile 2 blocks/CU
// (-20%: FETCH 2x + per-step amortization). Step = ~7170 cyc: MFMA pipe
// 52%, LDS ~32%, VALU 20%, HBM 28% -- structural plateau of the
// lockstep-barrier schedule. Remaining lever (pre-convert A + A-in-reg,
// LDS-B-only) nets ~0 (+23us convert pass vs ~20-30us gemm saving).
//
// Schedule: counted-lgkm read-ahead (A-fragment ds_reads issued one phase
// early, 16 outstanding = hw cap), ONE s_barrier per K-step, vmcnt(4)
// end-of-step (B(t+1) landed, A(t+2) in flight), vmcnt(0) only at t=30.
// ---------------------------------------------------------------------------
__global__ __launch_bounds__(512, 2) void gemm_logits_kernel(
    const float* __restrict__ query,
    const unsigned short* __restrict__ ph, const unsigned short* __restrict__ pl,
    const float* __restrict__ p2, float* __restrict__ out) {
    __shared__ unsigned short sAh[2][16 * 512];   // 2 x 16 KB
    __shared__ unsigned short sAl[2][16 * 512];   // 2 x 16 KB
    __shared__ unsigned short sBh[2][16 * 512];   // 2 x 16 KB
    __shared__ unsigned short sBl[2][16 * 512];   // 2 x 16 KB  (128 KB)

    const int tid = threadIdx.x;
    const int wave = tid >> 6;   // 0..7
    const int lane = tid & 63;
    const int wr = wave >> 2;    // 0..1: row half (128 rows)
    const int wc = wave & 3;     // 0..3: col quarter (64 cols)

    // XCD-aware: 8 chunks of 32 blocks; chunk = same col-tile, 32 row-tiles.
    const int b = blockIdx.x;            // 0..255
    const int v = (b & 7) * 32 + (b >> 3);
    const int colt = v >> 6;             // 0..3
    const int rowt = v & 63;             // 0..63
    const int row0 = rowt * 256;
    const int col0 = colt * 256;

    // B staging (R4-verified pre-swizzled source, linear gload_lds dest):
    const int rlB = lane >> 2;
    const int cioB = (lane & 3) ^ ((lane >> 3) & 3);
    const int halfB = wave >> 2;         // 0: hi, 1: lo
    const int sgB = wave & 3;
    const unsigned short* gB = (halfB ? pl : ph)
        + (size_t)(col0 + sgB * 64 + rlB) * D_K + cioB * 8;

    // A staging: wave covers rows wave*32..wave*32+31 (2 subtiles of 16).
    const int rlA = lane >> 2;          // 0..15
    const int cA = lane & 3;            // k-granule 0..3
    const AS1 float* gA = (const AS1 float*)query
        + (size_t)(row0 + wave * 32 + rlA) * D_K + cA * 8;
    const int wroff = (4 * rlA + (cA ^ ((rlA >> 1) & 3))) * 8;  // shorts

    // fragment read offsets (swizzle-matched, conflict-free, R4-verified)
    const int rsel = lane & 15;
    const int kq = lane >> 4;
    const int fragoff = (4 * rsel + (kq ^ ((rsel >> 1) & 3))) * 8;

    floatx4 zero = {0.0f, 0.0f, 0.0f, 0.0f};
    floatx4 acc[8][4];
#pragma unroll
    for (int i = 0; i < 8; ++i)
#pragma unroll
        for (int j = 0; j < 4; ++j) acc[i][j] = zero;

    floatx4 f0[2], f1[2];        // A prefetch regs (16 VGPR)
    bf16x8 bh[4], bl[4];         // B fragments (held one K-step)
    bf16x8 ah[2][2], al[2][2];   // A fragments, 2 reg-sets (read-ahead)

    auto issueA = [&](int kb) {
#pragma unroll
        for (int s = 0; s < 2; ++s) {
            const AS1 float* p = gA + (size_t)(s * 16) * D_K + kb;
            f0[s] = *(const AS1 floatx4*)p;
            f1[s] = *(const AS1 floatx4*)(p + 4);
        }
    };
    auto issueB = [&](int kb, int nxt) {
        unsigned short* dstB = (halfB ? sBl[nxt] : sBh[nxt]) + sgB * 4 * 512;
#pragma unroll
        for (int s = 0; s < 4; ++s)
            __builtin_amdgcn_global_load_lds(
                (const AS1 unsigned int*)(const void*)(gB + (size_t)(s * 16) * D_K + kb),
                (AS3 unsigned int*)(void*)(dstB + s * 512), 16, 0, 0);
    };
    auto writeA = [&](int nxt, int s) {
        uint4v hi, lo;
        split_chunk(f0[s], f1[s], &hi, &lo);
        const int off = (wave * 2 + s) * 512 + wroff;
        *(uint4v*)(sAh[nxt] + off) = hi;
        *(uint4v*)(sAl[nxt] + off) = lo;
    };
    auto ldBfrag = [&](int cur) {
#pragma unroll
        for (int j = 0; j < 4; ++j) {
            const int boff = (wc * 4 + j) * 512 + fragoff;
            bh[j] = *(const bf16x8*)(sBh[cur] + boff);
            bl[j] = *(const bf16x8*)(sBl[cur] + boff);
        }
    };
    auto ldA = [&](int cur, int i0, int set) {
#pragma unroll
        for (int t = 0; t < 2; ++t) {
            const int aoff = (wr * 8 + i0 + t) * 512 + fragoff;
            ah[set][t] = *(const bf16x8*)(sAh[cur] + aoff);
            al[set][t] = *(const bf16x8*)(sAl[cur] + aoff);
        }
    };
    auto mfma2 = [&](int i0, int set) {
#pragma unroll
        for (int j = 0; j < 4; ++j)
#pragma unroll
            for (int t = 0; t < 2; ++t) {
                acc[i0 + t][j] = __builtin_amdgcn_mfma_f32_16x16x32_bf16(ah[set][t], bh[j], acc[i0 + t][j], 0, 0, 0);
                acc[i0 + t][j] = __builtin_amdgcn_mfma_f32_16x16x32_bf16(ah[set][t], bl[j], acc[i0 + t][j], 0, 0, 0);
                acc[i0 + t][j] = __builtin_amdgcn_mfma_f32_16x16x32_bf16(al[set][t], bh[j], acc[i0 + t][j], 0, 0, 0);
            }
    };

#define LGKM_MFMA(n, i0, set)                                   \
    asm volatile("s_waitcnt lgkmcnt(" #n ")" ::: "memory");     \
    __builtin_amdgcn_sched_barrier(0);                          \
    __builtin_amdgcn_s_setprio(1);                              \
    mfma2(i0, set);                                             \
    __builtin_amdgcn_s_setprio(0);

    // One K-step. DS issue order: [B 8r][A01 4r][A23 4r] | [A45 4r] |
    // [A67 4r] | [W 4w]. Counted lgkm waits cover reads only (FIFO).
    // Vmem order: [B x4 gload_lds][A x4 loads]; end-of-step vmcnt(4).
    auto stepf = [&](int kbB, int kbA, int cur, int nxt, bool pfB, bool pfA) {
        if (pfB) issueB(kbB, nxt);
        ldBfrag(cur);                // 8 reads
        ldA(cur, 0, 0);              // 4 reads
        ldA(cur, 2, 1);              // 4 reads   [16 outstanding, hw cap]
        LGKM_MFMA(4, 0, 0)           // B+A01 done; A23 in flight under MFMA
        ldA(cur, 4, 0);
        LGKM_MFMA(4, 2, 1)           // A23 done; A45 in flight under MFMA
        ldA(cur, 6, 1);
        LGKM_MFMA(4, 4, 0)           // A45 done; A67 in flight under MFMA
        if (pfB) { writeA(nxt, 0); writeA(nxt, 1); }  // VALU + 4 ds_write
        if (pfA) issueA(kbA);        // f-regs free after split VALU
        if (pfB) { asm volatile("s_waitcnt lgkmcnt(4)" ::: "memory"); }
        else     { asm volatile("s_waitcnt lgkmcnt(0)" ::: "memory"); }
        __builtin_amdgcn_sched_barrier(0);
        __builtin_amdgcn_s_setprio(1);
        mfma2(6, 1);
        __builtin_amdgcn_s_setprio(0);
        asm volatile("s_waitcnt lgkmcnt(0)" ::: "memory");  // ds_writes drained
        if (pfB) {
            if (pfA) { asm volatile("s_waitcnt vmcnt(4)" ::: "memory"); }
            else     { asm volatile("s_waitcnt vmcnt(0)" ::: "memory"); }
        }
        __builtin_amdgcn_s_barrier();   // the ONE barrier per step
    };

    // prologue: tile 0 -> buf0; prefetch A(t1).
    issueA(0);                  // A(t0): oldest 4 vmem
    issueB(0, 0);               // B(t0): next 4
    writeA(0, 0);               // compiler waits vmcnt(4): A(t0) done, B in flight
    writeA(0, 1);
    issueA(32);                 // A(t1) in flight across the barrier
    asm volatile("s_waitcnt lgkmcnt(0)" ::: "memory");
    asm volatile("s_waitcnt vmcnt(4)" ::: "memory");   // B(t0) landed
    __builtin_amdgcn_s_barrier();

    for (int kt = 0; kt < 30; kt += 2) {
        stepf((kt + 1) * 32, (kt + 2) * 32, 0, 1, true, true);
        stepf((kt + 2) * 32, (kt + 3) * 32, 1, 0, true, true);
    }
    stepf(31 * 32, 0, 0, 1, true, false);   // t=30: stage t31, drain vmcnt(0)
    stepf(0, 0, 1, 0, false, false);        // t=31: compute only

#undef LGKM_MFMA

    // ---- epilogue: logits = 2*qp - p2[col] ----
    // C layout (verified m89/m91): col = lane&15, row = (lane>>4)*4 + reg
#pragma unroll
    for (int j = 0; j < 4; ++j) {
        const int gc = col0 + wc * 64 + j * 16 + rsel;
        const float p2v = p2[gc];
#pragma unroll
        for (int i = 0; i < 8; ++i) {
            const int gr = row0 + wr * 128 + i * 16 + kq * 4;
#pragma unroll
            for (int r = 0; r < 4; ++r) {
                out[(size_t)(gr + r) * M_P + gc] = 2.0f * acc[i][j][r] - p2v;
            }
        }
    }
}

// ---------------------------------------------------------------------------
// Fallback (tiny workspace): naive fp32 logits + separate softmax.
// ---------------------------------------------------------------------------
__global__ __launch_bounds__(256) void naive_logits_kernel(
    const float* __restrict__ query, const float* __restrict__ proto,
    float* __restrict__ out) {
    __shared__ float qs[D_K];
    int n = blockIdx.x;
    int t = threadIdx.x;
    ((float4*)qs)[t] = ((const float4*)(query + (size_t)n * D_K))[t];
    __syncthreads();
    float acc[4] = {0.f, 0.f, 0.f, 0.f};
    float pp[4] = {0.f, 0.f, 0.f, 0.f};
    for (int d = 0; d < D_K; d += 4) {
        float4 qv = *(const float4*)(qs + d);
#pragma unroll
        for (int j = 0; j < 4; ++j) {
            const float4 pv = *(const float4*)(proto + (size_t)(t + 256 * j) * D_K + d);
            acc[j] += qv.x * pv.x + qv.y * pv.y + qv.z * pv.z + qv.w * pv.w;
            pp[j] += pv.x * pv.x + pv.y * pv.y + pv.z * pv.z + pv.w * pv.w;
        }
    }
#pragma unroll
    for (int j = 0; j < 4; ++j)
        out[(size_t)n * M_P + t + 256 * j] = 2.0f * acc[j] - pp[j];
}

// ---------------------------------------------------------------------------
// In-place row softmax, wave-per-row (no LDS/barriers). ~24 us measured
// (~5.3 TB/s, near BW ceiling).
// ---------------------------------------------------------------------------
__global__ __launch_bounds__(256) void softmax_kernel(float* __restrict__ out) {
    const int lane = threadIdx.x & 63;
    int n = blockIdx.x * 4 + (threadIdx.x >> 6);
    for (int it = 0; it < 2; ++it, n += 8192) {
        float* row = out + (size_t)n * M_P;
        floatx4 v[4];
#pragma unroll
        for (int k = 0; k < 4; ++k)
            v[k] = *((const floatx4*)row + k * 64 + lane);
        float mx = fmaxf(fmaxf(v[0].x, v[0].y), fmaxf(v[0].z, v[0].w));
#pragma unroll
        for (int k = 1; k < 4; ++k)
            mx = fmaxf(mx, fmaxf(fmaxf(v[k].x, v[k].y), fmaxf(v[k].z, v[k].w)));
#pragma unroll
        for (int off = 1; off < 64; off <<= 1) mx = fmaxf(mx, __shfl_xor(mx, off));
        float s = 0.0f;
#pragma unroll
        for (int k = 0; k < 4; ++k) {
            v[k].x = __expf(v[k].x - mx);
            v[k].y = __expf(v[k].y - mx);
            v[k].z = __expf(v[k].z - mx);
            v[k].w = __expf(v[k].w - mx);
            s += v[k].x + v[k].y + v[k].z + v[k].w;
        }
#pragma unroll
        for (int off = 1; off < 64; off <<= 1) s += __shfl_xor(s, off);
        const float inv = 1.0f / s;
#pragma unroll
        for (int k = 0; k < 4; ++k) {
            floatx4 o;
            o.x = v[k].x * inv; o.y = v[k].y * inv;
            o.z = v[k].z * inv; o.w = v[k].w * inv;
            __builtin_nontemporal_store(o, (floatx4*)row + k * 64 + lane);
        }
    }
}

extern "C" void kernel_launch(void* const* d_in, const int* in_sizes, int n_in,
                              void* d_out, int out_size, void* d_ws, size_t ws_size,
                              hipStream_t stream) {
    const float* query = (const float*)d_in[0];
    const float* proto = (const float*)d_in[1];
    float* out = (float*)d_out;

    const size_t pElems = (size_t)M_P * D_K;   // 1M
    const size_t needed = pElems * 2 * 2 + M_P * 4;  // ~4.2 MiB

    if (ws_size >= needed) {
        unsigned short* ph = (unsigned short*)d_ws;
        unsigned short* pl = ph + pElems;
        float* p2 = (float*)(pl + pElems);

        convert_proto_kernel<<<M_P, 256, 0, stream>>>(proto, ph, pl, p2);
        gemm_logits_kernel<<<(N_Q / 256) * (M_P / 256), 512, 0, stream>>>(
            query, ph, pl, p2, out);
    } else {
        naive_logits_kernel<<<N_Q, 256, 0, stream>>>(query, proto, out);
    }
    softmax_kernel<<<2048, 256, 0, stream>>>(out);
}